// Round 5
// baseline (16140.347 us; speedup 1.0000x reference)
//
#include <hip/hip_runtime.h>

#define B_ 256
#define S_ 128
#define D_ 2
#define H_ 512
#define NBLK 256

__device__ __forceinline__ float sigm(float x){ return 1.f/(1.f+__expf(-x)); }
__device__ __forceinline__ float tanh_(float x){ return 1.f - 2.f/(__expf(2.f*x)+1.f); }

// Agent-scope (cross-XCD coherent, L2-bypassing) relaxed accesses — no flushes.
__device__ __forceinline__ float ldc(const float* p){
    return __hip_atomic_load(p, __ATOMIC_RELAXED, __HIP_MEMORY_SCOPE_AGENT);
}
__device__ __forceinline__ void stc(float* p, float v){
    __hip_atomic_store(p, v, __ATOMIC_RELAXED, __HIP_MEMORY_SCOPE_AGENT);
}

// Flush-free grid barrier. All stores drained (vmcnt(0) inside __syncthreads)
// before arrive; arrive/spin via agent-relaxed atomics at the IF$ coherence
// point. No buffer_wbl2/inv anywhere.
__device__ __forceinline__ void gbar(unsigned* bar){
    __syncthreads();
    if (threadIdx.x == 0) {
        asm volatile("s_waitcnt vmcnt(0)" ::: "memory");
        unsigned g = __hip_atomic_load(&bar[1], __ATOMIC_RELAXED, __HIP_MEMORY_SCOPE_AGENT);
        unsigned a = __hip_atomic_fetch_add(&bar[0], 1u, __ATOMIC_RELAXED, __HIP_MEMORY_SCOPE_AGENT);
        if (a == NBLK - 1u) {
            __hip_atomic_store(&bar[0], 0u, __ATOMIC_RELAXED, __HIP_MEMORY_SCOPE_AGENT);
            asm volatile("s_waitcnt vmcnt(0)" ::: "memory");
            __hip_atomic_store(&bar[1], g + 1u, __ATOMIC_RELAXED, __HIP_MEMORY_SCOPE_AGENT);
        } else {
            while (__hip_atomic_load(&bar[1], __ATOMIC_RELAXED, __HIP_MEMORY_SCOPE_AGENT) == g)
                __builtin_amdgcn_s_sleep(1);
        }
    }
    __syncthreads();
}

// ---------------------------------------------------------------------------
// prep: dxw[j] = dec_bih[j]+dec_bhh[j] - sum_k dec_Wih[j][k]  (dec input = -1)
//       ebias[j] = enc_bih[j]+enc_bhh[j]
// ---------------------------------------------------------------------------
__global__ __launch_bounds__(256) void prep5(
    const float* __restrict__ dWih, const float* __restrict__ dbih,
    const float* __restrict__ dbhh, const float* __restrict__ ebih,
    const float* __restrict__ ebhh, float* __restrict__ dxw,
    float* __restrict__ ebias)
{
    int j = blockIdx.x * 256 + threadIdx.x;
    const float* row = dWih + (size_t)j * H_;
    float s = 0.f;
    for (int k = 0; k < H_; k++) s += row[k];
    dxw[j]   = dbih[j] + dbhh[j] - s;
    ebias[j] = ebih[j] + ebhh[j];
}

// pack Whh into [jt 32][ks 8][i4 16][rw 64][c 4]: per-thread 64 weights
// lane-coalesced.  n>=2^20 selects decoder.
__global__ __launch_bounds__(256) void pack_whh(
    const float* __restrict__ eW, const float* __restrict__ dW,
    float* __restrict__ pe, float* __restrict__ pd)
{
    size_t n = (size_t)blockIdx.x * 256 + threadIdx.x;
    int sel = (int)(n >> 20);
    int m = (int)(n & 1048575);
    int c = m & 3, rw = (m >> 2) & 63, i4 = (m >> 8) & 15;
    int ks = (m >> 12) & 7, jt = m >> 15;
    int g = rw >> 4, hu = rw & 15;
    size_t src = (size_t)(g * H_ + jt * 16 + hu) * H_ + ks * 64 + i4 * 4 + c;
    if (sel) pd[m] = dW[src]; else pe[m] = eW[src];
}

__device__ __forceinline__ void load_w64(const float* Wsrc, int packed,
                                         int jt, int ks, int rw, float* w)
{
    if (packed) {
        const float4* wp = (const float4*)Wsrc + (size_t)(jt * 8 + ks) * 1024 + rw;
#pragma unroll
        for (int i = 0; i < 16; i++) {
            float4 t4 = wp[(size_t)i * 64];
            w[4*i]=t4.x; w[4*i+1]=t4.y; w[4*i+2]=t4.z; w[4*i+3]=t4.w;
        }
    } else {
        int g = rw >> 4, hu = rw & 15;
        const float4* wp = (const float4*)(Wsrc + (size_t)(g * H_ + jt*16 + hu) * H_ + ks * 64);
#pragma unroll
        for (int i = 0; i < 16; i++) {
            float4 t4 = wp[i];
            w[4*i]=t4.x; w[4*i+1]=t4.y; w[4*i+2]=t4.z; w[4*i+3]=t4.w;
        }
    }
}

// ---------------------------------------------------------------------------
// Persistent encoder: 256 blocks x 512 thr; block (bt 8 x jt 32): 32 batches,
// 16 hidden units (64 gate rows). Weights VGPR-resident for all 128 steps;
// c in registers; h exchanged via agent-relaxed (sc1) accesses.
// ---------------------------------------------------------------------------
__global__ __launch_bounds__(512, 1) void enc_p(
    const float* __restrict__ x, const float* __restrict__ eWih,
    const float* __restrict__ Wsrc, int packed,
    const float* __restrict__ ebias, float* __restrict__ enc_hs,
    float* __restrict__ c_fin, unsigned* bar)
{
    __shared__ float smem[16384];                  // 64KB: Hs / P overlay
    float (*Hs)[H_]    = (float (*)[H_])smem;      // [32][512]
    float (*P)[32][64] = (float (*)[32][64])smem;  // [ks][b][rw^swz]

    const int tid = threadIdx.x;
    const int ks = tid >> 6, rw = tid & 63;
    const int bt = blockIdx.x >> 5, jt = blockIdx.x & 31;
    const int b0 = bt * 32, hu0 = jt * 16;

    float w[64];
    load_w64(Wsrc, packed, jt, ks, rw, w);

    const int fb = tid >> 4, fh = tid & 15;
    const int fhu = hu0 + fh;
    float eb4[4], wi0[4], wi1[4];
#pragma unroll
    for (int g = 0; g < 4; g++) {
        eb4[g] = ebias[g*H_ + fhu];
        wi0[g] = eWih[(size_t)(g*H_ + fhu)*D_ + 0];
        wi1[g] = eWih[(size_t)(g*H_ + fhu)*D_ + 1];
    }
    float creg = 0.f;

    for (int t = 0; t < S_; t++) {
        float acc[32];
        if (t == 0) {
#pragma unroll
            for (int b = 0; b < 32; b++) acc[b] = 0.f;
        } else {
#pragma unroll 4
            for (int i = 0; i < 32; i++)
                Hs[i][tid] = ldc(&enc_hs[((size_t)(b0+i)*S_ + (t-1))*H_ + tid]);
            __syncthreads();
#pragma unroll 2
            for (int b = 0; b < 32; b++) {
                const float4* hp = (const float4*)&Hs[b][ks * 64];   // wave-uniform
                float s = 0.f;
#pragma unroll
                for (int i = 0; i < 16; i++) {
                    float4 h4 = hp[i];
                    s += h4.x*w[4*i] + h4.y*w[4*i+1] + h4.z*w[4*i+2] + h4.w*w[4*i+3];
                }
                acc[b] = s;
            }
            __syncthreads();
        }
#pragma unroll
        for (int b = 0; b < 32; b++) P[ks][b][rw ^ ((b & 3) << 4)] = acc[b];
        __syncthreads();
        {
            float z[4];
#pragma unroll
            for (int g = 0; g < 4; g++) {
                int row = g*16 + fh;
                float s2 = 0.f;
#pragma unroll
                for (int k8 = 0; k8 < 8; k8++)
                    s2 += P[k8][fb][row ^ ((fb & 3) << 4)];
                z[g] = s2 + eb4[g];
            }
            int bb = b0 + fb;
            float x0 = x[((size_t)bb*S_ + t)*D_ + 0];
            float x1 = x[((size_t)bb*S_ + t)*D_ + 1];
#pragma unroll
            for (int g = 0; g < 4; g++) z[g] += x0*wi0[g] + x1*wi1[g];
            float cn = sigm(z[1])*creg + sigm(z[0])*tanh_(z[2]);
            float hn = sigm(z[3])*tanh_(cn);
            creg = cn;
            stc(&enc_hs[((size_t)bb*S_ + t)*H_ + fhu], hn);
        }
        if (t < S_ - 1) gbar(bar);
    }
    stc(&c_fin[(size_t)(b0 + fb)*H_ + fhu], creg);
}

// ---------------------------------------------------------------------------
// fp32 GEMM for W1e: C[m][n] = sum_k A[m][k]*Bm[n][k] + bias[n]
// ---------------------------------------------------------------------------
template<int BM, int BN, int TM, int TN>
__global__ __launch_bounds__((BM/TM)*(BN/TN)) void gemm_bias(
    const float* __restrict__ A, const float* __restrict__ Bm,
    const float* __restrict__ bias, float* __restrict__ C,
    int M, int N, int K)
{
    constexpr int BK = 32;
    constexpr int TH = (BM / TM) * (BN / TN);
    constexpr int AL = BM * BK / TH;
    constexpr int BL = BN * BK / TH;
    constexpr int RP = TH / BK;
    __shared__ float As[BK][BM + 4];
    __shared__ float Bs[BK][BN + 4];
    const int tid = threadIdx.x;
    const int tn = tid % (BN / TN);
    const int tm = tid / (BN / TN);
    const int m0 = blockIdx.x * BM, n0 = blockIdx.y * BN;
    const int lk = tid % BK, lr = tid / BK;

    float acc[TM][TN];
#pragma unroll
    for (int i = 0; i < TM; i++)
#pragma unroll
        for (int j = 0; j < TN; j++) acc[i][j] = 0.f;

    float areg[AL], breg[BL];
#pragma unroll
    for (int i = 0; i < AL; i++) areg[i] = A[(size_t)(m0 + lr + i * RP) * K + lk];
#pragma unroll
    for (int i = 0; i < BL; i++) breg[i] = Bm[(size_t)(n0 + lr + i * RP) * K + lk];

    const int NC = K / BK;
    for (int c = 0; c < NC; c++) {
        __syncthreads();
#pragma unroll
        for (int i = 0; i < AL; i++) As[lk][lr + i * RP] = areg[i];
#pragma unroll
        for (int i = 0; i < BL; i++) Bs[lk][lr + i * RP] = breg[i];
        __syncthreads();
        if (c + 1 < NC) {
            int k0 = (c + 1) * BK;
#pragma unroll
            for (int i = 0; i < AL; i++) areg[i] = A[(size_t)(m0 + lr + i * RP) * K + k0 + lk];
#pragma unroll
            for (int i = 0; i < BL; i++) breg[i] = Bm[(size_t)(n0 + lr + i * RP) * K + k0 + lk];
        }
#pragma unroll
        for (int k = 0; k < BK; k++) {
            float av[TM], bvv[TN];
#pragma unroll
            for (int i = 0; i < TM; i++) av[i] = As[k][tm * TM + i];
#pragma unroll
            for (int j = 0; j < TN; j++) bvv[j] = Bs[k][tn * TN + j];
#pragma unroll
            for (int i = 0; i < TM; i++)
#pragma unroll
                for (int j = 0; j < TN; j++) acc[i][j] += av[i] * bvv[j];
        }
    }
#pragma unroll
    for (int i = 0; i < TM; i++) {
        int m = m0 + tm * TM + i;
#pragma unroll
        for (int j = 0; j < TN; j++) {
            int n = n0 + tn * TN + j;
            C[(size_t)m * N + n] = acc[i][j] + bias[n];
        }
    }
}

// ---------------------------------------------------------------------------
// Persistent decoder: per step {LSTM | gbar | W2h | gbar | attn | gbar}.
// Whh slice (64f) + W2 slice (16f) VGPR-resident whole kernel; c in regs.
// Cross-block data (h_dec, w2h, h_glim) via sc1; W1e/enc_hs plain cached.
// ---------------------------------------------------------------------------
__global__ __launch_bounds__(512, 1) void dec_p(
    const float* __restrict__ Wsrc, int packed,
    const float* __restrict__ dxw,
    const float* __restrict__ W2, const float* __restrict__ b2,
    const float* __restrict__ vv, const float* __restrict__ bv,
    const float* __restrict__ enc_hs, const float* __restrict__ W1e,
    const float* __restrict__ c_fin,
    float* __restrict__ h_dec, float* __restrict__ w2h,
    float* __restrict__ h_glim, float* __restrict__ out,
    unsigned* bar)
{
    __shared__ float smem[16384];
    float (*Hs)[H_]     = (float (*)[H_])smem;
    float (*P)[32][64]  = (float (*)[32][64])smem;   // lstm partials
    float (*P2)[32][16] = (float (*)[32][16])smem;   // w2h partials [b][p][j]
    float* qq  = smem;                               // attn overlays
    float* ua  = smem + 512;
    float* red = smem + 640;

    const int tid = threadIdx.x;
    const int ks = tid >> 6, rw = tid & 63;
    const int bt = blockIdx.x >> 5, jt = blockIdx.x & 31;
    const int b0 = bt * 32, hu0 = jt * 16;
    const int ln = tid & 63, wv = tid >> 6;

    float w[64];
    load_w64(Wsrc, packed, jt, ks, rw, w);

    const int rsub = (tid >> 4) & 3, jj = tid & 15;
    float w2r[16];
    {
        const float4* p4 = (const float4*)(W2 + (size_t)(hu0 + jj)*H_ + ks*64 + rsub*16);
#pragma unroll
        for (int i = 0; i < 4; i++) {
            float4 t4 = p4[i];
            w2r[4*i]=t4.x; w2r[4*i+1]=t4.y; w2r[4*i+2]=t4.z; w2r[4*i+3]=t4.w;
        }
    }

    const int fb = tid >> 4, fh = tid & 15;
    const int fhu = hu0 + fh;
    float db4[4];
#pragma unroll
    for (int g = 0; g < 4; g++) db4[g] = dxw[g*H_ + fhu];
    const float b2f = b2[fhu];
    float creg = c_fin[(size_t)(b0 + fb)*H_ + fhu];

    const int ab = blockIdx.x;                      // attention batch
    const float* w1b = W1e    + (size_t)ab * S_ * H_;
    const float* eb  = enc_hs + (size_t)ab * S_ * H_;
    const float4 vr0 = *(const float4*)(vv + ln*8);
    const float4 vr1 = *(const float4*)(vv + ln*8 + 4);
    const float bvr = bv[0];

    for (int t = 0; t < S_; t++) {
        // ---------------- phase L: LSTM ----------------
        {
            const float* hsrc = (t == 0) ? (enc_hs + (size_t)(S_-1)*H_) : h_glim;
            const size_t hstr = (t == 0) ? (size_t)(S_*H_) : (size_t)H_;
#pragma unroll 4
            for (int i = 0; i < 32; i++)
                Hs[i][tid] = ldc(&hsrc[(size_t)(b0+i)*hstr + tid]);
            __syncthreads();
            float acc[32];
#pragma unroll 2
            for (int b = 0; b < 32; b++) {
                const float4* hp = (const float4*)&Hs[b][ks * 64];
                float s = 0.f;
#pragma unroll
                for (int i = 0; i < 16; i++) {
                    float4 h4 = hp[i];
                    s += h4.x*w[4*i] + h4.y*w[4*i+1] + h4.z*w[4*i+2] + h4.w*w[4*i+3];
                }
                acc[b] = s;
            }
            __syncthreads();
#pragma unroll
            for (int b = 0; b < 32; b++) P[ks][b][rw ^ ((b & 3) << 4)] = acc[b];
            __syncthreads();
            float z[4];
#pragma unroll
            for (int g = 0; g < 4; g++) {
                int row = g*16 + fh;
                float s2 = 0.f;
#pragma unroll
                for (int k8 = 0; k8 < 8; k8++)
                    s2 += P[k8][fb][row ^ ((fb & 3) << 4)];
                z[g] = s2 + db4[g];
            }
            float cn = sigm(z[1])*creg + sigm(z[0])*tanh_(z[2]);
            float hn = sigm(z[3])*tanh_(cn);
            creg = cn;
            stc(&h_dec[(size_t)(b0 + fb)*H_ + fhu], hn);
        }
        gbar(bar);
        // ---------------- phase W: w2h ----------------
        {
#pragma unroll 4
            for (int i = 0; i < 32; i++)
                Hs[i][tid] = ldc(&h_dec[(size_t)(b0+i)*H_ + tid]);
            __syncthreads();
            float a2[32];
#pragma unroll 2
            for (int b = 0; b < 32; b++) {
                const float4* hp = (const float4*)&Hs[b][ks*64 + rsub*16];
                float s = 0.f;
#pragma unroll
                for (int i = 0; i < 4; i++) {
                    float4 h4 = hp[i];
                    s += h4.x*w2r[4*i] + h4.y*w2r[4*i+1] + h4.z*w2r[4*i+2] + h4.w*w2r[4*i+3];
                }
                a2[b] = s;
            }
            __syncthreads();
#pragma unroll
            for (int b = 0; b < 32; b++) P2[b][ks*4 + rsub][jj] = a2[b];
            __syncthreads();
            float s2 = 0.f;
#pragma unroll
            for (int p = 0; p < 32; p++) s2 += P2[fb][p][fh];
            stc(&w2h[(size_t)(b0 + fb)*H_ + fhu], s2 + b2f);
        }
        gbar(bar);
        // ---------------- phase A: attention ----------------
        {
            qq[tid] = ldc(&w2h[(size_t)ab*H_ + tid]);
            __syncthreads();
            float4 q0 = *(float4*)&qq[ln*8];
            float4 q1 = *(float4*)&qq[ln*8 + 4];
#pragma unroll 2
            for (int si = 0; si < 16; si++) {
                int s = wv*16 + si;
                const float4* rp = (const float4*)(w1b + (size_t)s*H_ + ln*8);
                float4 r0 = rp[0], r1 = rp[1];
                float sum = tanh_(r0.x+q0.x)*vr0.x + tanh_(r0.y+q0.y)*vr0.y
                          + tanh_(r0.z+q0.z)*vr0.z + tanh_(r0.w+q0.w)*vr0.w
                          + tanh_(r1.x+q1.x)*vr1.x + tanh_(r1.y+q1.y)*vr1.y
                          + tanh_(r1.z+q1.z)*vr1.z + tanh_(r1.w+q1.w)*vr1.w;
#pragma unroll
                for (int off = 32; off; off >>= 1) sum += __shfl_xor(sum, off);
                if (ln == 0) ua[s] = sum + bvr;
            }
            __syncthreads();
            float e = 0.f;
            if (tid < 128) {
                float m = ua[tid];
#pragma unroll
                for (int off = 32; off; off >>= 1) m = fmaxf(m, __shfl_xor(m, off));
                if (ln == 0) red[tid >> 6] = m;
            }
            __syncthreads();
            if (tid < 128) {
                float mx = fmaxf(red[0], red[1]);
                e = __expf(ua[tid] - mx);
                float ss = e;
#pragma unroll
                for (int off = 32; off; off >>= 1) ss += __shfl_xor(ss, off);
                if (ln == 0) red[2 + (tid >> 6)] = ss;
            }
            __syncthreads();
            if (tid < 128) {
                float a = e / (red[2] + red[3]);
                ua[tid] = a;
                out[(size_t)ab*S_*S_ + (size_t)t*S_ + tid] = a;
            }
            __syncthreads();
            float ga = 0.f;
#pragma unroll 4
            for (int s = 0; s < S_; s++) ga += ua[s] * eb[(size_t)s*H_ + tid];
            stc(&h_glim[(size_t)ab*H_ + tid], ga);
        }
        if (t < S_ - 1) gbar(bar);
    }
}

// ---------------------------------------------------------------------------
extern "C" void kernel_launch(void* const* d_in, const int* in_sizes, int n_in,
                              void* d_out, int out_size, void* d_ws, size_t ws_size,
                              hipStream_t stream)
{
    const float* x    = (const float*)d_in[0];
    const float* eWih = (const float*)d_in[1];
    const float* eWhh = (const float*)d_in[2];
    const float* ebih = (const float*)d_in[3];
    const float* ebhh = (const float*)d_in[4];
    const float* dWih = (const float*)d_in[5];
    const float* dWhh = (const float*)d_in[6];
    const float* dbih = (const float*)d_in[7];
    const float* dbhh = (const float*)d_in[8];
    const float* W1   = (const float*)d_in[9];
    const float* b1   = (const float*)d_in[10];
    const float* W2   = (const float*)d_in[11];
    const float* b2   = (const float*)d_in[12];
    const float* vv   = (const float*)d_in[13];
    const float* bv   = (const float*)d_in[14];
    float* out = (float*)d_out;

    float* ws     = (float*)d_ws;
    float* enc_hs = ws;                                    // B*S*H
    float* W1e    = enc_hs + (size_t)B_ * S_ * H_;         // B*S*H
    float* h_dec  = W1e    + (size_t)B_ * S_ * H_;         // B*H
    float* h_glim = h_dec  + (size_t)B_ * H_;              // B*H
    float* w2h    = h_glim + (size_t)B_ * H_;              // B*H
    float* c_fin  = w2h    + (size_t)B_ * H_;              // B*H
    float* dxw    = c_fin  + (size_t)B_ * H_;              // 2048
    float* ebias  = dxw    + 2048;                         // 2048
    unsigned* bars = (unsigned*)(ebias + 2048);            // 8 u32
    float* wpk_e  = (float*)(bars + 8);                    // 1048576 (optional)
    float* wpk_d  = wpk_e + 1048576;                       // 1048576 (optional)

    size_t base_f = (size_t)(wpk_e - ws);
    int packed = (ws_size >= (base_f + 2097152u) * sizeof(float)) ? 1 : 0;

    hipMemsetAsync(bars, 0, 8 * sizeof(unsigned), stream);
    prep5<<<8, 256, 0, stream>>>(dWih, dbih, dbhh, ebih, ebhh, dxw, ebias);
    if (packed)
        pack_whh<<<8192, 256, 0, stream>>>(eWhh, dWhh, wpk_e, wpk_d);

    const float* We = packed ? wpk_e : eWhh;
    const float* Wd = packed ? wpk_d : dWhh;

    enc_p<<<NBLK, 512, 0, stream>>>(x, eWih, We, packed, ebias, enc_hs, c_fin, bars);

    gemm_bias<128, 128, 8, 8><<<dim3((B_ * S_) / 128, H_ / 128), 256, 0, stream>>>(
        enc_hs, W1, b1, W1e, B_ * S_, H_, H_);

    dec_p<<<NBLK, 512, 0, stream>>>(Wd, packed, dxw, W2, b2, vv, bv,
                                    enc_hs, W1e, c_fin,
                                    h_dec, w2h, h_glim, out, bars + 4);
}

// Round 6
// 11915.925 us; speedup vs baseline: 1.3545x; 1.3545x over previous
//
#include <hip/hip_runtime.h>
#include <hip/hip_fp16.h>

#define B_ 256
#define S_ 128
#define D_ 2
#define H_ 512
#define NBLK 256

struct alignas(16) H8 { __half2 h[4]; };

__device__ __forceinline__ float sigm(float x){ return 1.f/(1.f+__expf(-x)); }
__device__ __forceinline__ float tanh_(float x){ return 1.f - 2.f/(__expf(2.f*x)+1.f); }

// Agent-scope relaxed (sc1: L2-bypass, LLC-coherent) accesses — no cache flushes.
__device__ __forceinline__ float ldc(const float* p){
    return __hip_atomic_load(p, __ATOMIC_RELAXED, __HIP_MEMORY_SCOPE_AGENT);
}
__device__ __forceinline__ void stc(float* p, float v){
    __hip_atomic_store(p, v, __ATOMIC_RELAXED, __HIP_MEMORY_SCOPE_AGENT);
}
__device__ __forceinline__ unsigned ldu(const unsigned* p){
    return __hip_atomic_load(p, __ATOMIC_RELAXED, __HIP_MEMORY_SCOPE_AGENT);
}
__device__ __forceinline__ void stu(unsigned* p, unsigned v){
    __hip_atomic_store(p, v, __ATOMIC_RELAXED, __HIP_MEMORY_SCOPE_AGENT);
}

// Hierarchical flush-free grid barrier: 16 groups of 16 blocks.
// Counters padded to 64B lines. Stores drained (vmcnt) before arrive.
__device__ __forceinline__ void gbar(unsigned* bar){
    __syncthreads();
    if (threadIdx.x == 0) {
        asm volatile("s_waitcnt vmcnt(0)" ::: "memory");
        const int grp = blockIdx.x >> 4;
        unsigned* gc = bar + grp * 16;
        unsigned* gg = bar + 256 + grp * 16;
        unsigned* rc = bar + 512;
        unsigned* rg = bar + 528;
        unsigned gen = ldu(gg);
        if (__hip_atomic_fetch_add(gc, 1u, __ATOMIC_RELAXED, __HIP_MEMORY_SCOPE_AGENT) == 15u) {
            stu(gc, 0u);
            unsigned rgen = ldu(rg);
            if (__hip_atomic_fetch_add(rc, 1u, __ATOMIC_RELAXED, __HIP_MEMORY_SCOPE_AGENT) == 15u) {
                stu(rc, 0u);
                stu(rg, rgen + 1u);
            } else {
                while (ldu(rg) == rgen) __builtin_amdgcn_s_sleep(1);
            }
            stu(gg, gen + 1u);
        } else {
            while (ldu(gg) == gen) __builtin_amdgcn_s_sleep(1);
        }
    }
    __syncthreads();
}

// Batched sc1 stage: 32 rows of h into registers first (one latency), then LDS.
__device__ __forceinline__ void stage32(float (*Hs)[H_], const float* src,
                                        size_t str, int b0, int tid){
    float r[32];
#pragma unroll
    for (int i = 0; i < 32; i++) r[i] = ldc(src + (size_t)(b0 + i) * str + tid);
#pragma unroll
    for (int i = 0; i < 32; i++) Hs[i][tid] = r[i];
}

// ---------------------------------------------------------------------------
__global__ __launch_bounds__(256) void prep6(
    const float* __restrict__ dWih, const float* __restrict__ dbih,
    const float* __restrict__ dbhh, const float* __restrict__ ebih,
    const float* __restrict__ ebhh, float* __restrict__ dxw,
    float* __restrict__ ebias)
{
    int j = blockIdx.x * 256 + threadIdx.x;
    const float* row = dWih + (size_t)j * H_;
    float s = 0.f;
    for (int k = 0; k < H_; k++) s += row[k];
    dxw[j]   = dbih[j] + dbhh[j] - s;
    ebias[j] = ebih[j] + ebhh[j];
}

__global__ __launch_bounds__(256) void pack_whh(
    const float* __restrict__ eW, const float* __restrict__ dW,
    float* __restrict__ pe, float* __restrict__ pd)
{
    size_t n = (size_t)blockIdx.x * 256 + threadIdx.x;
    int sel = (int)(n >> 20);
    int m = (int)(n & 1048575);
    int c = m & 3, rw = (m >> 2) & 63, i4 = (m >> 8) & 15;
    int ks = (m >> 12) & 7, jt = m >> 15;
    int g = rw >> 4, hu = rw & 15;
    size_t src = (size_t)(g * H_ + jt * 16 + hu) * H_ + ks * 64 + i4 * 4 + c;
    if (sel) pd[m] = dW[src]; else pe[m] = eW[src];
}

__device__ __forceinline__ void load_w64(const float* Wsrc, int packed,
                                         int jt, int ks, int rw, float* w)
{
    if (packed) {
        const float4* wp = (const float4*)Wsrc + (size_t)(jt * 8 + ks) * 1024 + rw;
#pragma unroll
        for (int i = 0; i < 16; i++) {
            float4 t4 = wp[(size_t)i * 64];
            w[4*i]=t4.x; w[4*i+1]=t4.y; w[4*i+2]=t4.z; w[4*i+3]=t4.w;
        }
    } else {
        int g = rw >> 4, hu = rw & 15;
        const float4* wp = (const float4*)(Wsrc + (size_t)(g * H_ + jt*16 + hu) * H_ + ks * 64);
#pragma unroll
        for (int i = 0; i < 16; i++) {
            float4 t4 = wp[i];
            w[4*i]=t4.x; w[4*i+1]=t4.y; w[4*i+2]=t4.z; w[4*i+3]=t4.w;
        }
    }
}

// ---------------------------------------------------------------------------
// Persistent encoder. Also mirrors h into fp16 (eh16) for dec_p's glimpse.
// ---------------------------------------------------------------------------
__global__ __launch_bounds__(512, 1) void enc_p(
    const float* __restrict__ x, const float* __restrict__ eWih,
    const float* __restrict__ Wsrc, int packed,
    const float* __restrict__ ebias, float* __restrict__ enc_hs,
    __half* __restrict__ eh16, float* __restrict__ c_fin, unsigned* bar)
{
    __shared__ float smem[16384];
    float (*Hs)[H_]    = (float (*)[H_])smem;
    float (*P)[32][64] = (float (*)[32][64])smem;

    const int tid = threadIdx.x;
    const int ks = tid >> 6, rw = tid & 63;
    const int bt = blockIdx.x >> 5, jt = blockIdx.x & 31;
    const int b0 = bt * 32, hu0 = jt * 16;

    float w[64];
    load_w64(Wsrc, packed, jt, ks, rw, w);

    const int fb = tid >> 4, fh = tid & 15;
    const int fhu = hu0 + fh;
    float eb4[4], wi0[4], wi1[4];
#pragma unroll
    for (int g = 0; g < 4; g++) {
        eb4[g] = ebias[g*H_ + fhu];
        wi0[g] = eWih[(size_t)(g*H_ + fhu)*D_ + 0];
        wi1[g] = eWih[(size_t)(g*H_ + fhu)*D_ + 1];
    }
    float creg = 0.f;

    for (int t = 0; t < S_; t++) {
        float acc[32];
        if (t == 0) {
#pragma unroll
            for (int b = 0; b < 32; b++) acc[b] = 0.f;
        } else {
            stage32(Hs, enc_hs + (size_t)(t - 1) * H_, (size_t)S_ * H_, b0, tid);
            __syncthreads();
#pragma unroll 2
            for (int b = 0; b < 32; b++) {
                const float4* hp = (const float4*)&Hs[b][ks * 64];   // wave-uniform
                float s = 0.f;
#pragma unroll
                for (int i = 0; i < 16; i++) {
                    float4 h4 = hp[i];
                    s += h4.x*w[4*i] + h4.y*w[4*i+1] + h4.z*w[4*i+2] + h4.w*w[4*i+3];
                }
                acc[b] = s;
            }
            __syncthreads();
        }
#pragma unroll
        for (int b = 0; b < 32; b++) P[ks][b][rw ^ ((b & 3) << 4)] = acc[b];
        __syncthreads();
        {
            float z[4];
#pragma unroll
            for (int g = 0; g < 4; g++) {
                int row = g*16 + fh;
                float s2 = 0.f;
#pragma unroll
                for (int k8 = 0; k8 < 8; k8++)
                    s2 += P[k8][fb][row ^ ((fb & 3) << 4)];
                z[g] = s2 + eb4[g];
            }
            int bb = b0 + fb;
            float x0 = x[((size_t)bb*S_ + t)*D_ + 0];
            float x1 = x[((size_t)bb*S_ + t)*D_ + 1];
#pragma unroll
            for (int g = 0; g < 4; g++) z[g] += x0*wi0[g] + x1*wi1[g];
            float cn = sigm(z[1])*creg + sigm(z[0])*tanh_(z[2]);
            float hn = sigm(z[3])*tanh_(cn);
            creg = cn;
            stc(&enc_hs[((size_t)bb*S_ + t)*H_ + fhu], hn);
            if (eh16) eh16[((size_t)bb*S_ + t)*H_ + fhu] = __float2half(hn);
        }
        if (t < S_ - 1) gbar(bar);
    }
    stc(&c_fin[(size_t)(b0 + fb)*H_ + fhu], creg);
}

// ---------------------------------------------------------------------------
// fp32 GEMM, templated output type (half for W1e16).
// ---------------------------------------------------------------------------
template<int BM, int BN, int TM, int TN, typename OT>
__global__ __launch_bounds__((BM/TM)*(BN/TN)) void gemm_bias(
    const float* __restrict__ A, const float* __restrict__ Bm,
    const float* __restrict__ bias, OT* __restrict__ C,
    int M, int N, int K)
{
    constexpr int BK = 32;
    constexpr int TH = (BM / TM) * (BN / TN);
    constexpr int AL = BM * BK / TH;
    constexpr int BL = BN * BK / TH;
    constexpr int RP = TH / BK;
    __shared__ float As[BK][BM + 4];
    __shared__ float Bs[BK][BN + 4];
    const int tid = threadIdx.x;
    const int tn = tid % (BN / TN);
    const int tm = tid / (BN / TN);
    const int m0 = blockIdx.x * BM, n0 = blockIdx.y * BN;
    const int lk = tid % BK, lr = tid / BK;

    float acc[TM][TN];
#pragma unroll
    for (int i = 0; i < TM; i++)
#pragma unroll
        for (int j = 0; j < TN; j++) acc[i][j] = 0.f;

    float areg[AL], breg[BL];
#pragma unroll
    for (int i = 0; i < AL; i++) areg[i] = A[(size_t)(m0 + lr + i * RP) * K + lk];
#pragma unroll
    for (int i = 0; i < BL; i++) breg[i] = Bm[(size_t)(n0 + lr + i * RP) * K + lk];

    const int NC = K / BK;
    for (int c = 0; c < NC; c++) {
        __syncthreads();
#pragma unroll
        for (int i = 0; i < AL; i++) As[lk][lr + i * RP] = areg[i];
#pragma unroll
        for (int i = 0; i < BL; i++) Bs[lk][lr + i * RP] = breg[i];
        __syncthreads();
        if (c + 1 < NC) {
            int k0 = (c + 1) * BK;
#pragma unroll
            for (int i = 0; i < AL; i++) areg[i] = A[(size_t)(m0 + lr + i * RP) * K + k0 + lk];
#pragma unroll
            for (int i = 0; i < BL; i++) breg[i] = Bm[(size_t)(n0 + lr + i * RP) * K + k0 + lk];
        }
#pragma unroll
        for (int k = 0; k < BK; k++) {
            float av[TM], bvv[TN];
#pragma unroll
            for (int i = 0; i < TM; i++) av[i] = As[k][tm * TM + i];
#pragma unroll
            for (int j = 0; j < TN; j++) bvv[j] = Bs[k][tn * TN + j];
#pragma unroll
            for (int i = 0; i < TM; i++)
#pragma unroll
                for (int j = 0; j < TN; j++) acc[i][j] += av[i] * bvv[j];
        }
    }
#pragma unroll
    for (int i = 0; i < TM; i++) {
        int m = m0 + tm * TM + i;
#pragma unroll
        for (int j = 0; j < TN; j++) {
            int n = n0 + tn * TN + j;
            C[(size_t)m * N + n] = (OT)(acc[i][j] + bias[n]);
        }
    }
}

// ---------------------------------------------------------------------------
// Persistent decoder: {LSTM | gbar | W2h | gbar | attn | gbar} per step.
// W1e16/eb16 are fp16, read-only, plain cached loads (L2-resident).
// ---------------------------------------------------------------------------
__global__ __launch_bounds__(512, 1) void dec_p(
    const float* __restrict__ Wsrc, int packed,
    const float* __restrict__ dxw,
    const float* __restrict__ W2, const float* __restrict__ b2,
    const float* __restrict__ vv, const float* __restrict__ bv,
    const float* __restrict__ enc_hs, const __half* __restrict__ W1e16,
    const __half* __restrict__ eb16, const float* __restrict__ c_fin,
    float* __restrict__ h_dec, float* __restrict__ w2h,
    float* __restrict__ h_glim, float* __restrict__ out,
    unsigned* bar)
{
    __shared__ float smem[16384];
    float (*Hs)[H_]     = (float (*)[H_])smem;
    float (*P)[32][64]  = (float (*)[32][64])smem;
    float (*P2)[32][16] = (float (*)[32][16])smem;
    float* qq  = smem;
    float* ua  = smem + 512;
    float* red = smem + 640;
    float* P3  = smem + 1024;     // [8][64][9]

    const int tid = threadIdx.x;
    const int ks = tid >> 6, rw = tid & 63;
    const int bt = blockIdx.x >> 5, jt = blockIdx.x & 31;
    const int b0 = bt * 32, hu0 = jt * 16;
    const int ln = tid & 63, wv = tid >> 6;

    float w[64];
    load_w64(Wsrc, packed, jt, ks, rw, w);

    const int rsub = (tid >> 4) & 3, jj = tid & 15;
    float w2r[16];
    {
        const float4* p4 = (const float4*)(W2 + (size_t)(hu0 + jj)*H_ + ks*64 + rsub*16);
#pragma unroll
        for (int i = 0; i < 4; i++) {
            float4 t4 = p4[i];
            w2r[4*i]=t4.x; w2r[4*i+1]=t4.y; w2r[4*i+2]=t4.z; w2r[4*i+3]=t4.w;
        }
    }

    const int fb = tid >> 4, fh = tid & 15;
    const int fhu = hu0 + fh;
    float db4[4];
#pragma unroll
    for (int g = 0; g < 4; g++) db4[g] = dxw[g*H_ + fhu];
    const float b2f = b2[fhu];
    float creg = c_fin[(size_t)(b0 + fb)*H_ + fhu];

    const int ab = blockIdx.x;
    const __half* w1b = W1e16 + (size_t)ab * S_ * H_;
    const __half* ebh = eb16 ? (eb16 + (size_t)ab * S_ * H_) : (const __half*)nullptr;
    const float* ebf = enc_hs + (size_t)ab * S_ * H_;
    const float4 vr0 = *(const float4*)(vv + ln*8);
    const float4 vr1 = *(const float4*)(vv + ln*8 + 4);
    const float bvr = bv[0];

    for (int t = 0; t < S_; t++) {
        // ---------------- phase L: LSTM ----------------
        {
            const float* hsrc = (t == 0) ? (enc_hs + (size_t)(S_-1)*H_) : h_glim;
            const size_t hstr = (t == 0) ? (size_t)(S_*H_) : (size_t)H_;
            stage32(Hs, hsrc, hstr, b0, tid);
            __syncthreads();
            float acc[32];
#pragma unroll 2
            for (int b = 0; b < 32; b++) {
                const float4* hp = (const float4*)&Hs[b][ks * 64];
                float s = 0.f;
#pragma unroll
                for (int i = 0; i < 16; i++) {
                    float4 h4 = hp[i];
                    s += h4.x*w[4*i] + h4.y*w[4*i+1] + h4.z*w[4*i+2] + h4.w*w[4*i+3];
                }
                acc[b] = s;
            }
            __syncthreads();
#pragma unroll
            for (int b = 0; b < 32; b++) P[ks][b][rw ^ ((b & 3) << 4)] = acc[b];
            __syncthreads();
            float z[4];
#pragma unroll
            for (int g = 0; g < 4; g++) {
                int row = g*16 + fh;
                float s2 = 0.f;
#pragma unroll
                for (int k8 = 0; k8 < 8; k8++)
                    s2 += P[k8][fb][row ^ ((fb & 3) << 4)];
                z[g] = s2 + db4[g];
            }
            float cn = sigm(z[1])*creg + sigm(z[0])*tanh_(z[2]);
            float hn = sigm(z[3])*tanh_(cn);
            creg = cn;
            stc(&h_dec[(size_t)(b0 + fb)*H_ + fhu], hn);
        }
        gbar(bar);
        // ---------------- phase W: w2h ----------------
        {
            stage32(Hs, h_dec, (size_t)H_, b0, tid);
            __syncthreads();
            float a2[32];
#pragma unroll 2
            for (int b = 0; b < 32; b++) {
                const float4* hp = (const float4*)&Hs[b][ks*64 + rsub*16];
                float s = 0.f;
#pragma unroll
                for (int i = 0; i < 4; i++) {
                    float4 h4 = hp[i];
                    s += h4.x*w2r[4*i] + h4.y*w2r[4*i+1] + h4.z*w2r[4*i+2] + h4.w*w2r[4*i+3];
                }
                a2[b] = s;
            }
            __syncthreads();
#pragma unroll
            for (int b = 0; b < 32; b++) P2[b][ks*4 + rsub][jj] = a2[b];
            __syncthreads();
            float s2 = 0.f;
#pragma unroll
            for (int p = 0; p < 32; p++) s2 += P2[fb][p][fh];
            stc(&w2h[(size_t)(b0 + fb)*H_ + fhu], s2 + b2f);
        }
        gbar(bar);
        // ---------------- phase A: attention ----------------
        {
            qq[tid] = ldc(&w2h[(size_t)ab*H_ + tid]);
            __syncthreads();
            float4 q0 = *(float4*)&qq[ln*8];
            float4 q1 = *(float4*)&qq[ln*8 + 4];
#pragma unroll 4
            for (int si = 0; si < 16; si++) {
                int s = wv*16 + si;
                H8 w8 = *(const H8*)(w1b + (size_t)s*H_ + ln*8);
                float2 a0 = __half22float2(w8.h[0]);
                float2 a1 = __half22float2(w8.h[1]);
                float2 a2 = __half22float2(w8.h[2]);
                float2 a3 = __half22float2(w8.h[3]);
                float sum = tanh_(a0.x+q0.x)*vr0.x + tanh_(a0.y+q0.y)*vr0.y
                          + tanh_(a1.x+q0.z)*vr0.z + tanh_(a1.y+q0.w)*vr0.w
                          + tanh_(a2.x+q1.x)*vr1.x + tanh_(a2.y+q1.y)*vr1.y
                          + tanh_(a3.x+q1.z)*vr1.z + tanh_(a3.y+q1.w)*vr1.w;
#pragma unroll
                for (int off = 32; off; off >>= 1) sum += __shfl_xor(sum, off);
                if (ln == 0) ua[s] = sum + bvr;
            }
            __syncthreads();
            float e = 0.f;
            if (tid < 128) {
                float m = ua[tid];
#pragma unroll
                for (int off = 32; off; off >>= 1) m = fmaxf(m, __shfl_xor(m, off));
                if (ln == 0) red[tid >> 6] = m;
            }
            __syncthreads();
            if (tid < 128) {
                float mx = fmaxf(red[0], red[1]);
                e = __expf(ua[tid] - mx);
                float ss = e;
#pragma unroll
                for (int off = 32; off; off >>= 1) ss += __shfl_xor(ss, off);
                if (ln == 0) red[2 + (tid >> 6)] = ss;
            }
            __syncthreads();
            if (tid < 128) {
                float a = e / (red[2] + red[3]);
                ua[tid] = a;
                out[(size_t)ab*S_*S_ + (size_t)t*S_ + tid] = a;
            }
            __syncthreads();
            // glimpse: each wave covers 16 s-rows, lane owns 8 columns
            float acc8[8];
#pragma unroll
            for (int i = 0; i < 8; i++) acc8[i] = 0.f;
            if (ebh) {
#pragma unroll 4
                for (int si = 0; si < 16; si++) {
                    int s = wv*16 + si;
                    H8 e8 = *(const H8*)(ebh + (size_t)s*H_ + ln*8);
                    float a = ua[s];
                    float2 p0 = __half22float2(e8.h[0]);
                    float2 p1 = __half22float2(e8.h[1]);
                    float2 p2 = __half22float2(e8.h[2]);
                    float2 p3 = __half22float2(e8.h[3]);
                    acc8[0] += a*p0.x; acc8[1] += a*p0.y;
                    acc8[2] += a*p1.x; acc8[3] += a*p1.y;
                    acc8[4] += a*p2.x; acc8[5] += a*p2.y;
                    acc8[6] += a*p3.x; acc8[7] += a*p3.y;
                }
            } else {
#pragma unroll 4
                for (int si = 0; si < 16; si++) {
                    int s = wv*16 + si;
                    const float4* ep = (const float4*)(ebf + (size_t)s*H_ + ln*8);
                    float4 e0 = ep[0], e1 = ep[1];
                    float a = ua[s];
                    acc8[0] += a*e0.x; acc8[1] += a*e0.y;
                    acc8[2] += a*e0.z; acc8[3] += a*e0.w;
                    acc8[4] += a*e1.x; acc8[5] += a*e1.y;
                    acc8[6] += a*e1.z; acc8[7] += a*e1.w;
                }
            }
#pragma unroll
            for (int i = 0; i < 8; i++) P3[wv*576 + ln*9 + i] = acc8[i];
            __syncthreads();
            {
                float g = 0.f;
                int base = (tid >> 3) * 9 + (tid & 7);
#pragma unroll
                for (int w8 = 0; w8 < 8; w8++) g += P3[w8*576 + base];
                stc(&h_glim[(size_t)ab*H_ + tid], g);
            }
        }
        if (t < S_ - 1) gbar(bar);
    }
}

// ---------------------------------------------------------------------------
extern "C" void kernel_launch(void* const* d_in, const int* in_sizes, int n_in,
                              void* d_out, int out_size, void* d_ws, size_t ws_size,
                              hipStream_t stream)
{
    const float* x    = (const float*)d_in[0];
    const float* eWih = (const float*)d_in[1];
    const float* eWhh = (const float*)d_in[2];
    const float* ebih = (const float*)d_in[3];
    const float* ebhh = (const float*)d_in[4];
    const float* dWih = (const float*)d_in[5];
    const float* dWhh = (const float*)d_in[6];
    const float* dbih = (const float*)d_in[7];
    const float* dbhh = (const float*)d_in[8];
    const float* W1   = (const float*)d_in[9];
    const float* b1   = (const float*)d_in[10];
    const float* W2   = (const float*)d_in[11];
    const float* b2   = (const float*)d_in[12];
    const float* vv   = (const float*)d_in[13];
    const float* bv   = (const float*)d_in[14];
    float* out = (float*)d_out;

    float* ws      = (float*)d_ws;
    float* enc_hs  = ws;                                   // 16777216
    float* h_dec   = enc_hs + (size_t)B_ * S_ * H_;        // 131072
    float* h_glim  = h_dec  + (size_t)B_ * H_;
    float* w2h     = h_glim + (size_t)B_ * H_;
    float* c_fin   = w2h    + (size_t)B_ * H_;
    float* dxw     = c_fin  + (size_t)B_ * H_;             // 2048
    float* ebias   = dxw    + 2048;                        // 2048
    unsigned* bars = (unsigned*)(ebias + 2048);            // 2048 u32
    __half* W1e16  = (__half*)(ebias + 2048 + 2048);       // 16777216 halfs = 8388608 f
    float* after16 = (float*)(W1e16) + 8388608;
    __half* eh16   = (__half*)after16;                     // optional, 8388608 f
    float* wpk_e   = after16 + 8388608;                    // optional
    float* wpk_d   = wpk_e + 1048576;

    size_t mand_f   = (size_t)(after16 - ws);              // mandatory floats
    int have_eh16 = (ws_size >= (mand_f + 8388608u) * sizeof(float)) ? 1 : 0;
    int packed    = (ws_size >= (mand_f + 8388608u + 2097152u) * sizeof(float)) ? 1 : 0;
    if (!have_eh16) eh16 = nullptr;

    hipMemsetAsync(bars, 0, 2048 * sizeof(unsigned), stream);
    prep6<<<8, 256, 0, stream>>>(dWih, dbih, dbhh, ebih, ebhh, dxw, ebias);
    if (packed)
        pack_whh<<<8192, 256, 0, stream>>>(eWhh, dWhh, wpk_e, wpk_d);

    const float* We = packed ? wpk_e : eWhh;
    const float* Wd = packed ? wpk_d : dWhh;

    enc_p<<<NBLK, 512, 0, stream>>>(x, eWih, We, packed, ebias, enc_hs, eh16, c_fin, bars);

    gemm_bias<128, 128, 8, 8, __half>
        <<<dim3((B_ * S_) / 128, H_ / 128), 256, 0, stream>>>(
        enc_hs, W1, b1, W1e16, B_ * S_, H_, H_);

    dec_p<<<NBLK, 512, 0, stream>>>(Wd, packed, dxw, W2, b2, vv, bv,
                                    enc_hs, W1e16, eh16, c_fin,
                                    h_dec, w2h, h_glim, out, bars + 1024);
}